// Round 4
// baseline (238.229 us; speedup 1.0000x reference)
//
#include <hip/hip_runtime.h>
#include <stdint.h>

typedef __attribute__((ext_vector_type(4))) short short4v;
typedef __attribute__((ext_vector_type(8))) short bf16x8;
typedef __attribute__((ext_vector_type(4))) float f32x4;
typedef __attribute__((ext_vector_type(2))) uint32_t uint2v;
typedef __attribute__((ext_vector_type(4))) uint32_t uint4v;
typedef __attribute__((ext_vector_type(4))) uint16_t ushort4v;

#define NN 4096

__device__ __forceinline__ uint16_t f2bf(float f) {
    union { float f; uint32_t u; } c; c.f = f;
    uint32_t r = c.u + 0x7FFF + ((c.u >> 16) & 1);   // RNE
    return (uint16_t)(r >> 16);
}

// ---------------------------------------------------------------------------
// Kernel 1: adjacency -> bitmask; weights -> bf16 transposed.
// Wq gets 1/sqrt(32) * log2(e) folded in (attn uses exp2 directly).
// ---------------------------------------------------------------------------
__global__ __launch_bounds__(256) void pack_kernel(
    const int* __restrict__ adj, uint64_t* __restrict__ bits,
    const float* __restrict__ Wq, const float* __restrict__ Wk,
    const float* __restrict__ Wv, const float* __restrict__ Wo,
    uint16_t* __restrict__ WT, uint16_t* __restrict__ WoT)
{
    const int lane = threadIdx.x & 63;
    const int wave = (blockIdx.x * blockDim.x + threadIdx.x) >> 6;
    const int nwaves = (gridDim.x * blockDim.x) >> 6;
    const int TOT = (NN * NN) / 64;
    for (int i = wave; i < TOT; i += nwaves) {
        int v = adj[(size_t)i * 64 + lane];
        uint64_t m = __ballot(v != 0);
        if (lane == 0) bits[i] = m;
    }
    const int tid = blockIdx.x * blockDim.x + threadIdx.x;
    const int nth = gridDim.x * blockDim.x;
    for (int t = tid; t < 3 * 128 * 128 + 128 * 128; t += nth) {
        if (t < 3 * 128 * 128) {
            int j = t >> 7, k = t & 127;
            int m = j >> 7, jj = j & 127;
            const float* W = (m == 0) ? Wq : ((m == 1) ? Wk : Wv);
            float v = W[k * 128 + jj];
            if (m == 0) v *= (0.17677669529663687f * 1.4426950408889634f);
            WT[t] = f2bf(v);
        } else {
            int t2 = t - 3 * 128 * 128;
            int j = t2 >> 7, k = t2 & 127;
            WoT[t2] = f2bf(Wo[k * 128 + j]);
        }
    }
}

// ---------------------------------------------------------------------------
// Kernel 2: fused QKV projection.
// Q: row-major [bh][n][32] bf16. Kf: MFMA B-fragment order.
// Vf: MFMA A-fragment order for PV, produced via SWAPPED mfma(xb, af) so each
// lane's 4 results are 4 consecutive u16s -> single 8B store (was 4x 2B
// scattered stores).
// ---------------------------------------------------------------------------
__global__ __launch_bounds__(256) void qkv_kernel(
    const float* __restrict__ x, const uint16_t* __restrict__ WT,
    uint16_t* __restrict__ Q, uint16_t* __restrict__ Kf, uint16_t* __restrict__ Vf)
{
    const int wave = threadIdx.x >> 6, lane = threadIdx.x & 63;
    const int g = lane >> 4, l15 = lane & 15;
    const int ntile = blockIdx.x * 4 + wave;
    const int n = ntile * 16 + l15;
    const int b = n >> 12, nn = n & 4095;

    const char* xrow = (const char*)x + (size_t)n * 512;
    bf16x8 xb[4];
#pragma unroll
    for (int ks = 0; ks < 4; ++ks) {
        f32x4 a = *(const f32x4*)(xrow + ks * 128 + g * 16);
        f32x4 c = *(const f32x4*)(xrow + ks * 128 + 64 + g * 16);
        bf16x8 f;
#pragma unroll
        for (int i = 0; i < 4; ++i) { f[i] = (short)f2bf(a[i]); f[4 + i] = (short)f2bf(c[i]); }
        xb[ks] = f;
    }

#pragma unroll 1
    for (int jt = 0; jt < 24; ++jt) {
        const int j0 = jt * 16;
        const bool isV = (j0 >= 256);
        const char* wrow = (const char*)WT + (size_t)(j0 + l15) * 256;
        f32x4 acc = {0.f, 0.f, 0.f, 0.f};
#pragma unroll
        for (int ks = 0; ks < 4; ++ks) {
            short4v a0 = *(const short4v*)(wrow + ks * 64 + g * 8);
            short4v a1 = *(const short4v*)(wrow + ks * 64 + 32 + g * 8);
            bf16x8 af = __builtin_shufflevector(a0, a1, 0, 1, 2, 3, 4, 5, 6, 7);
            acc = isV ? __builtin_amdgcn_mfma_f32_16x16x32_bf16(xb[ks], af, acc, 0, 0, 0)
                      : __builtin_amdgcn_mfma_f32_16x16x32_bf16(af, xb[ks], acc, 0, 0, 0);
        }
        const int m = j0 >> 7;
        const int bh = b * 4 + ((j0 & 127) >> 5);
        const int half = (j0 >> 4) & 1;
        ushort4v st;
#pragma unroll
        for (int r = 0; r < 4; ++r) st[r] = f2bf(acc[r]);
        if (m == 0) {
            const int d0 = (j0 & 31) + g * 4;
            *(ushort4v*)(Q + ((size_t)bh * 4096 + nn) * 32 + d0) = st;
        } else if (m == 1) {
            *(ushort4v*)(Kf + ((size_t)bh << 17) + (ntile & 255) * 512 + lane * 8 + half * 4) = st;
        } else {
            // lane holds V[key = ntile*16 + g*4 + r][d = half*16 + l15], r=0..3
            *(ushort4v*)(Vf + ((size_t)bh << 17) + ((ntile & 255) >> 1) * 1024
                         + half * 512 + lane * 8 + ((ntile & 1) << 2)) = st;
        }
    }
}

// ---------------------------------------------------------------------------
// Kernel 3: flash attention, LDS-free main loop, TLP-based latency hiding.
// Block = 8 waves (512 thr), 64 q-rows; waves split the key dim 8-way
// (512 keys each, exact under fixed-max softmax). Single-buffered register
// loads (no dbuf) -> low VGPR -> ~5 waves/SIMD resident. 3-stage LDS combine.
// ---------------------------------------------------------------------------
__global__ __launch_bounds__(512, 5) void attn_kernel(
    const uint16_t* __restrict__ Q, const uint16_t* __restrict__ Kf,
    const uint16_t* __restrict__ Vf, const uint32_t* __restrict__ bits,
    uint16_t* __restrict__ O)
{
    __shared__ f32x4 cmb[4][4][2][64];   // [wavepair][qg][h][lane]
    __shared__ float csum[4][4][64];
    const int tid = threadIdx.x;
    const int wave = tid >> 6, lane = tid & 63;
    const int g = lane >> 4, l15 = lane & 15, gsh = g * 4;
    const int blk = blockIdx.x;
    const int bh = ((blk & 7) << 1) | ((blk >> 3) & 1);   // XCD-cluster bh
    const int qb = blk >> 4;
    const int q0 = qb * 64;

    const char* Kp = (const char*)Kf + ((size_t)bh << 18) + wave * 32768 + lane * 16;
    const char* Vp = (const char*)Vf + ((size_t)bh << 18) + wave * 32768 + lane * 16;
    const uint32_t* ap[4];
#pragma unroll
    for (int qg = 0; qg < 4; ++qg)
        ap[qg] = bits + (size_t)(q0 + qg * 16 + l15) * 128 + wave * 16;

    bf16x8 qf[4];
#pragma unroll
    for (int qg = 0; qg < 4; ++qg) {
        const char* qrow = (const char*)Q + ((size_t)bh * 4096 + q0 + qg * 16 + l15) * 64;
        short4v a0 = *(const short4v*)(qrow + g * 8);
        short4v a1 = *(const short4v*)(qrow + 32 + g * 8);
        qf[qg] = __builtin_shufflevector(a0, a1, 0, 1, 2, 3, 4, 5, 6, 7);
    }

    bf16x8 ones;
#pragma unroll
    for (int i = 0; i < 8; ++i) ones[i] = (short)0x3F80;   // bf16 1.0

    const f32x4 z = {0.f, 0.f, 0.f, 0.f};
    f32x4 o[4][2], sacc[4];
#pragma unroll
    for (int qg = 0; qg < 4; ++qg) { o[qg][0] = z; o[qg][1] = z; sacc[qg] = z; }

#pragma unroll 1
    for (int t = 0; t < 8; ++t) {
        bf16x8 kc[4], vc[4];
#pragma unroll
        for (int j = 0; j < 4; ++j) kc[j] = *(const bf16x8*)(Kp + j * 1024);
#pragma unroll
        for (int i = 0; i < 4; ++i) vc[i] = *(const bf16x8*)(Vp + i * 1024);
        Kp += 4096; Vp += 4096;
        uint2v wc[4];
#pragma unroll
        for (int qg = 0; qg < 4; ++qg) { wc[qg] = *(const uint2v*)ap[qg]; ap[qg] += 2; }

#pragma unroll
        for (int qg = 0; qg < 4; ++qg) {
            f32x4 s[4];
#pragma unroll
            for (int j = 0; j < 4; ++j)
                s[j] = __builtin_amdgcn_mfma_f32_16x16x32_bf16(kc[j], qf[qg], z, 0, 0, 0);
            float p[16];
#pragma unroll
            for (int j = 0; j < 4; ++j) {
                uint32_t wj = wc[qg][j >> 1] >> (((j & 1) << 4) + gsh);
#pragma unroll
                for (int r = 0; r < 4; ++r) {
                    float pv = __builtin_amdgcn_exp2f(s[j][r]);
                    int msk = ((int)(wj << (31 - r))) >> 31;
                    p[j * 4 + r] = __uint_as_float(__float_as_uint(pv) & (uint32_t)msk);
                }
            }
            uint32_t pk[8];
#pragma unroll
            for (int i = 0; i < 8; ++i) {
                uint32_t r_;
                asm("v_cvt_pk_bf16_f32 %0, %1, %2" : "=v"(r_) : "v"(p[2 * i]), "v"(p[2 * i + 1]));
                pk[i] = r_;
            }
            uint4v u0 = {pk[0], pk[1], pk[2], pk[3]};
            uint4v u1 = {pk[4], pk[5], pk[6], pk[7]};
            bf16x8 pf0 = __builtin_bit_cast(bf16x8, u0);
            bf16x8 pf1 = __builtin_bit_cast(bf16x8, u1);
            o[qg][0] = __builtin_amdgcn_mfma_f32_16x16x32_bf16(vc[0], pf0, o[qg][0], 0, 0, 0);
            o[qg][0] = __builtin_amdgcn_mfma_f32_16x16x32_bf16(vc[2], pf1, o[qg][0], 0, 0, 0);
            o[qg][1] = __builtin_amdgcn_mfma_f32_16x16x32_bf16(vc[1], pf0, o[qg][1], 0, 0, 0);
            o[qg][1] = __builtin_amdgcn_mfma_f32_16x16x32_bf16(vc[3], pf1, o[qg][1], 0, 0, 0);
            sacc[qg] = __builtin_amdgcn_mfma_f32_16x16x32_bf16(ones, pf0, sacc[qg], 0, 0, 0);
            sacc[qg] = __builtin_amdgcn_mfma_f32_16x16x32_bf16(ones, pf1, sacc[qg], 0, 0, 0);
        }
    }

    // 3-stage combine across the 8 key-split waves
    if (wave < 4) {
#pragma unroll
        for (int qg = 0; qg < 4; ++qg) {
            cmb[wave][qg][0][lane] = o[qg][0];
            cmb[wave][qg][1][lane] = o[qg][1];
            csum[wave][qg][lane] = sacc[qg][0];
        }
    }
    __syncthreads();
    if (wave >= 4) {
        const int w2 = wave - 4;
#pragma unroll
        for (int qg = 0; qg < 4; ++qg) {
            cmb[w2][qg][0][lane] += o[qg][0];
            cmb[w2][qg][1][lane] += o[qg][1];
            csum[w2][qg][lane] += sacc[qg][0];
        }
    }
    __syncthreads();
    {
        const int qg = wave & 3, h = wave >> 2;   // each wave finalizes one (qg,h)
        f32x4 a = cmb[0][qg][h][lane] + cmb[1][qg][h][lane]
                + cmb[2][qg][h][lane] + cmb[3][qg][h][lane];
        float sd = csum[0][qg][lane] + csum[1][qg][lane]
                 + csum[2][qg][lane] + csum[3][qg][lane];
        const float inv = 1.0f / sd;
        const int q = q0 + qg * 16 + l15;
        uint16_t* orow = O + ((size_t)bh * 4096 + q) * 32;
        ushort4v st;
#pragma unroll
        for (int r = 0; r < 4; ++r) st[r] = f2bf(a[r] * inv);
        *(ushort4v*)(orow + h * 16 + gsh) = st;
    }
}

// ---------------------------------------------------------------------------
// Kernel 4: output projection.
// ---------------------------------------------------------------------------
__global__ __launch_bounds__(256) void proj_kernel(
    const uint16_t* __restrict__ A, const uint16_t* __restrict__ WoT,
    const float* __restrict__ bo, float* __restrict__ out)
{
    const int wave = threadIdx.x >> 6, lane = threadIdx.x & 63;
    const int g = lane >> 4, l15 = lane & 15;
    const int ntile = blockIdx.x * 4 + wave;
    const int n = ntile * 16 + l15;
    const int b = n >> 12, nn = n & 4095;

    bf16x8 bfr[4];
#pragma unroll
    for (int h = 0; h < 4; ++h) {
        const char* arow = (const char*)A + (((size_t)(b * 4 + h)) * 4096 + nn) * 64;
        short4v a0 = *(const short4v*)(arow + g * 8);
        short4v a1 = *(const short4v*)(arow + 32 + g * 8);
        bfr[h] = __builtin_shufflevector(a0, a1, 0, 1, 2, 3, 4, 5, 6, 7);
    }
#pragma unroll 1
    for (int ct = 0; ct < 8; ++ct) {
        const int c0 = ct * 16;
        const char* wrow = (const char*)WoT + (size_t)(c0 + l15) * 256;
        f32x4 acc = {0.f, 0.f, 0.f, 0.f};
#pragma unroll
        for (int h = 0; h < 4; ++h) {
            short4v a0 = *(const short4v*)(wrow + h * 64 + g * 8);
            short4v a1 = *(const short4v*)(wrow + h * 64 + 32 + g * 8);
            bf16x8 af = __builtin_shufflevector(a0, a1, 0, 1, 2, 3, 4, 5, 6, 7);
            acc = __builtin_amdgcn_mfma_f32_16x16x32_bf16(af, bfr[h], acc, 0, 0, 0);
        }
        f32x4 bias = *(const f32x4*)(bo + c0 + g * 4);
#pragma unroll
        for (int r = 0; r < 4; ++r) acc[r] += bias[r];
        *(f32x4*)(out + (size_t)n * 128 + c0 + g * 4) = acc;
    }
}

// ---------------------------------------------------------------------------
extern "C" void kernel_launch(void* const* d_in, const int* in_sizes, int n_in,
                              void* d_out, int out_size, void* d_ws, size_t ws_size,
                              hipStream_t stream)
{
    const float* x   = (const float*)d_in[0];
    const int*   adj = (const int*)d_in[1];
    const float* Wq  = (const float*)d_in[2];
    const float* Wk  = (const float*)d_in[3];
    const float* Wv  = (const float*)d_in[4];
    const float* Wo  = (const float*)d_in[5];
    const float* bo  = (const float*)d_in[6];
    float* out = (float*)d_out;

    char* ws = (char*)d_ws;
    uint16_t* Q    = (uint16_t*)(ws);                       // 4 MB
    uint16_t* Kf   = (uint16_t*)(ws + ((size_t)4 << 20));   // 4 MB (fragment order)
    uint16_t* Vf   = (uint16_t*)(ws + ((size_t)8 << 20));   // 4 MB (fragment order)
    uint16_t* AO   = (uint16_t*)(ws + ((size_t)12 << 20));  // 4 MB
    uint32_t* bits = (uint32_t*)(ws + ((size_t)16 << 20));  // 2 MB
    uint16_t* WT   = (uint16_t*)(ws + ((size_t)18 << 20));  // 96 KB
    uint16_t* WoT  = (uint16_t*)(ws + ((size_t)18 << 20) + 98304); // 32 KB

    hipLaunchKernelGGL(pack_kernel, dim3(2048), dim3(256), 0, stream,
                       adj, (uint64_t*)bits, Wq, Wk, Wv, Wo, WT, WoT);
    hipLaunchKernelGGL(qkv_kernel, dim3(256), dim3(256), 0, stream,
                       x, WT, Q, Kf, Vf);
    hipLaunchKernelGGL(attn_kernel, dim3(1024), dim3(512), 0, stream,
                       Q, Kf, Vf, bits, AO);
    hipLaunchKernelGGL(proj_kernel, dim3(256), dim3(256), 0, stream,
                       AO, WoT, bo, out);
}

// Round 5
// 133.177 us; speedup vs baseline: 1.7888x; 1.7888x over previous
//
#include <hip/hip_runtime.h>
#include <stdint.h>

typedef __attribute__((ext_vector_type(4))) short short4v;
typedef __attribute__((ext_vector_type(8))) short bf16x8;
typedef __attribute__((ext_vector_type(4))) float f32x4;
typedef __attribute__((ext_vector_type(2))) uint32_t uint2v;
typedef __attribute__((ext_vector_type(4))) uint32_t uint4v;
typedef __attribute__((ext_vector_type(4))) uint16_t ushort4v;

#define NN 4096

__device__ __forceinline__ uint16_t f2bf(float f) {
    union { float f; uint32_t u; } c; c.f = f;
    uint32_t r = c.u + 0x7FFF + ((c.u >> 16) & 1);   // RNE
    return (uint16_t)(r >> 16);
}

// ---------------------------------------------------------------------------
// Kernel 1: adjacency -> bitmask; weights -> bf16 transposed.
// Wq gets 1/sqrt(32) * log2(e) folded in (attn uses exp2 directly).
// ---------------------------------------------------------------------------
__global__ __launch_bounds__(256) void pack_kernel(
    const int* __restrict__ adj, uint64_t* __restrict__ bits,
    const float* __restrict__ Wq, const float* __restrict__ Wk,
    const float* __restrict__ Wv, const float* __restrict__ Wo,
    uint16_t* __restrict__ WT, uint16_t* __restrict__ WoT)
{
    const int lane = threadIdx.x & 63;
    const int wave = (blockIdx.x * blockDim.x + threadIdx.x) >> 6;
    const int nwaves = (gridDim.x * blockDim.x) >> 6;
    const int TOT = (NN * NN) / 64;
    for (int i = wave; i < TOT; i += nwaves) {
        int v = adj[(size_t)i * 64 + lane];
        uint64_t m = __ballot(v != 0);
        if (lane == 0) bits[i] = m;
    }
    const int tid = blockIdx.x * blockDim.x + threadIdx.x;
    const int nth = gridDim.x * blockDim.x;
    for (int t = tid; t < 3 * 128 * 128 + 128 * 128; t += nth) {
        if (t < 3 * 128 * 128) {
            int j = t >> 7, k = t & 127;
            int m = j >> 7, jj = j & 127;
            const float* W = (m == 0) ? Wq : ((m == 1) ? Wk : Wv);
            float v = W[k * 128 + jj];
            if (m == 0) v *= (0.17677669529663687f * 1.4426950408889634f);
            WT[t] = f2bf(v);
        } else {
            int t2 = t - 3 * 128 * 128;
            int j = t2 >> 7, k = t2 & 127;
            WoT[t2] = f2bf(Wo[k * 128 + j]);
        }
    }
}

// ---------------------------------------------------------------------------
// Kernel 2: fused QKV projection.
// Q: row-major [bh][n][32] bf16. Kf: MFMA B-fragment order.
// Vf: MFMA A-fragment order for PV, produced via SWAPPED mfma(xb, af) so each
// lane's 4 results are 4 consecutive u16s -> single 8B store.
// ---------------------------------------------------------------------------
__global__ __launch_bounds__(256) void qkv_kernel(
    const float* __restrict__ x, const uint16_t* __restrict__ WT,
    uint16_t* __restrict__ Q, uint16_t* __restrict__ Kf, uint16_t* __restrict__ Vf)
{
    const int wave = threadIdx.x >> 6, lane = threadIdx.x & 63;
    const int g = lane >> 4, l15 = lane & 15;
    const int ntile = blockIdx.x * 4 + wave;
    const int n = ntile * 16 + l15;
    const int b = n >> 12, nn = n & 4095;

    const char* xrow = (const char*)x + (size_t)n * 512;
    bf16x8 xb[4];
#pragma unroll
    for (int ks = 0; ks < 4; ++ks) {
        f32x4 a = *(const f32x4*)(xrow + ks * 128 + g * 16);
        f32x4 c = *(const f32x4*)(xrow + ks * 128 + 64 + g * 16);
        bf16x8 f;
#pragma unroll
        for (int i = 0; i < 4; ++i) { f[i] = (short)f2bf(a[i]); f[4 + i] = (short)f2bf(c[i]); }
        xb[ks] = f;
    }

#pragma unroll 1
    for (int jt = 0; jt < 24; ++jt) {
        const int j0 = jt * 16;
        const bool isV = (j0 >= 256);
        const char* wrow = (const char*)WT + (size_t)(j0 + l15) * 256;
        f32x4 acc = {0.f, 0.f, 0.f, 0.f};
#pragma unroll
        for (int ks = 0; ks < 4; ++ks) {
            short4v a0 = *(const short4v*)(wrow + ks * 64 + g * 8);
            short4v a1 = *(const short4v*)(wrow + ks * 64 + 32 + g * 8);
            bf16x8 af = __builtin_shufflevector(a0, a1, 0, 1, 2, 3, 4, 5, 6, 7);
            acc = isV ? __builtin_amdgcn_mfma_f32_16x16x32_bf16(xb[ks], af, acc, 0, 0, 0)
                      : __builtin_amdgcn_mfma_f32_16x16x32_bf16(af, xb[ks], acc, 0, 0, 0);
        }
        const int m = j0 >> 7;
        const int bh = b * 4 + ((j0 & 127) >> 5);
        const int half = (j0 >> 4) & 1;
        ushort4v st;
#pragma unroll
        for (int r = 0; r < 4; ++r) st[r] = f2bf(acc[r]);
        if (m == 0) {
            const int d0 = (j0 & 31) + g * 4;
            *(ushort4v*)(Q + ((size_t)bh * 4096 + nn) * 32 + d0) = st;
        } else if (m == 1) {
            *(ushort4v*)(Kf + ((size_t)bh << 17) + (ntile & 255) * 512 + lane * 8 + half * 4) = st;
        } else {
            // lane holds V[key = ntile*16 + g*4 + r][d = half*16 + l15], r=0..3
            *(ushort4v*)(Vf + ((size_t)bh << 17) + ((ntile & 255) >> 1) * 1024
                         + half * 512 + lane * 8 + ((ntile & 1) << 2)) = st;
        }
    }
}

// ---------------------------------------------------------------------------
// Kernel 3: flash attention, LDS-free main loop, TLP-based latency hiding.
// Block = 8 waves (512 thr), 64 q-rows; waves split the key dim 8-way
// (512 keys each, exact under fixed-max softmax).
// __launch_bounds__(512, 2): VGPR cap 128 — fits the ~108-VGPR state WITHOUT
// spilling (round 4's (512,5) forced a 102-cap -> scratch spill -> 400MB of
// scratch traffic). 2 blocks/CU resident = 4 waves/SIMD.
// ---------------------------------------------------------------------------
__global__ __launch_bounds__(512, 2) void attn_kernel(
    const uint16_t* __restrict__ Q, const uint16_t* __restrict__ Kf,
    const uint16_t* __restrict__ Vf, const uint32_t* __restrict__ bits,
    uint16_t* __restrict__ O)
{
    __shared__ f32x4 cmb[4][4][2][64];   // [wavepair][qg][h][lane]
    __shared__ float csum[4][4][64];
    const int tid = threadIdx.x;
    const int wave = tid >> 6, lane = tid & 63;
    const int g = lane >> 4, l15 = lane & 15, gsh = g * 4;
    const int blk = blockIdx.x;
    const int bh = ((blk & 7) << 1) | ((blk >> 3) & 1);   // XCD-cluster bh
    const int qb = blk >> 4;
    const int q0 = qb * 64;

    const char* Kp = (const char*)Kf + ((size_t)bh << 18) + wave * 32768 + lane * 16;
    const char* Vp = (const char*)Vf + ((size_t)bh << 18) + wave * 32768 + lane * 16;
    const uint32_t* ap[4];
#pragma unroll
    for (int qg = 0; qg < 4; ++qg)
        ap[qg] = bits + (size_t)(q0 + qg * 16 + l15) * 128 + wave * 16;

    bf16x8 qf[4];
#pragma unroll
    for (int qg = 0; qg < 4; ++qg) {
        const char* qrow = (const char*)Q + ((size_t)bh * 4096 + q0 + qg * 16 + l15) * 64;
        short4v a0 = *(const short4v*)(qrow + g * 8);
        short4v a1 = *(const short4v*)(qrow + 32 + g * 8);
        qf[qg] = __builtin_shufflevector(a0, a1, 0, 1, 2, 3, 4, 5, 6, 7);
    }

    bf16x8 ones;
#pragma unroll
    for (int i = 0; i < 8; ++i) ones[i] = (short)0x3F80;   // bf16 1.0

    const f32x4 z = {0.f, 0.f, 0.f, 0.f};
    f32x4 o[4][2], sacc[4];
#pragma unroll
    for (int qg = 0; qg < 4; ++qg) { o[qg][0] = z; o[qg][1] = z; sacc[qg] = z; }

#pragma unroll 1
    for (int t = 0; t < 8; ++t) {
        bf16x8 kc[4], vc[4];
#pragma unroll
        for (int j = 0; j < 4; ++j) kc[j] = *(const bf16x8*)(Kp + j * 1024);
#pragma unroll
        for (int i = 0; i < 4; ++i) vc[i] = *(const bf16x8*)(Vp + i * 1024);
        Kp += 4096; Vp += 4096;
        uint2v wc[4];
#pragma unroll
        for (int qg = 0; qg < 4; ++qg) { wc[qg] = *(const uint2v*)ap[qg]; ap[qg] += 2; }

#pragma unroll
        for (int qg = 0; qg < 4; ++qg) {
            f32x4 s[4];
#pragma unroll
            for (int j = 0; j < 4; ++j)
                s[j] = __builtin_amdgcn_mfma_f32_16x16x32_bf16(kc[j], qf[qg], z, 0, 0, 0);
            float p[16];
#pragma unroll
            for (int j = 0; j < 4; ++j) {
                uint32_t wj = wc[qg][j >> 1] >> (((j & 1) << 4) + gsh);
#pragma unroll
                for (int r = 0; r < 4; ++r) {
                    float pv = __builtin_amdgcn_exp2f(s[j][r]);
                    int msk = ((int)(wj << (31 - r))) >> 31;
                    p[j * 4 + r] = __uint_as_float(__float_as_uint(pv) & (uint32_t)msk);
                }
            }
            uint32_t pk[8];
#pragma unroll
            for (int i = 0; i < 8; ++i) {
                uint32_t r_;
                asm("v_cvt_pk_bf16_f32 %0, %1, %2" : "=v"(r_) : "v"(p[2 * i]), "v"(p[2 * i + 1]));
                pk[i] = r_;
            }
            uint4v u0 = {pk[0], pk[1], pk[2], pk[3]};
            uint4v u1 = {pk[4], pk[5], pk[6], pk[7]};
            bf16x8 pf0 = __builtin_bit_cast(bf16x8, u0);
            bf16x8 pf1 = __builtin_bit_cast(bf16x8, u1);
            o[qg][0] = __builtin_amdgcn_mfma_f32_16x16x32_bf16(vc[0], pf0, o[qg][0], 0, 0, 0);
            o[qg][0] = __builtin_amdgcn_mfma_f32_16x16x32_bf16(vc[2], pf1, o[qg][0], 0, 0, 0);
            o[qg][1] = __builtin_amdgcn_mfma_f32_16x16x32_bf16(vc[1], pf0, o[qg][1], 0, 0, 0);
            o[qg][1] = __builtin_amdgcn_mfma_f32_16x16x32_bf16(vc[3], pf1, o[qg][1], 0, 0, 0);
            sacc[qg] = __builtin_amdgcn_mfma_f32_16x16x32_bf16(ones, pf0, sacc[qg], 0, 0, 0);
            sacc[qg] = __builtin_amdgcn_mfma_f32_16x16x32_bf16(ones, pf1, sacc[qg], 0, 0, 0);
        }
    }

    // 3-stage combine across the 8 key-split waves
    if (wave < 4) {
#pragma unroll
        for (int qg = 0; qg < 4; ++qg) {
            cmb[wave][qg][0][lane] = o[qg][0];
            cmb[wave][qg][1][lane] = o[qg][1];
            csum[wave][qg][lane] = sacc[qg][0];
        }
    }
    __syncthreads();
    if (wave >= 4) {
        const int w2 = wave - 4;
#pragma unroll
        for (int qg = 0; qg < 4; ++qg) {
            cmb[w2][qg][0][lane] += o[qg][0];
            cmb[w2][qg][1][lane] += o[qg][1];
            csum[w2][qg][lane] += sacc[qg][0];
        }
    }
    __syncthreads();
    {
        const int qg = wave & 3, h = wave >> 2;   // each wave finalizes one (qg,h)
        f32x4 a = cmb[0][qg][h][lane] + cmb[1][qg][h][lane]
                + cmb[2][qg][h][lane] + cmb[3][qg][h][lane];
        float sd = csum[0][qg][lane] + csum[1][qg][lane]
                 + csum[2][qg][lane] + csum[3][qg][lane];
        const float inv = 1.0f / sd;
        const int q = q0 + qg * 16 + l15;
        uint16_t* orow = O + ((size_t)bh * 4096 + q) * 32;
        ushort4v st;
#pragma unroll
        for (int r = 0; r < 4; ++r) st[r] = f2bf(a[r] * inv);
        *(ushort4v*)(orow + h * 16 + gsh) = st;
    }
}

// ---------------------------------------------------------------------------
// Kernel 4: output projection.
// ---------------------------------------------------------------------------
__global__ __launch_bounds__(256) void proj_kernel(
    const uint16_t* __restrict__ A, const uint16_t* __restrict__ WoT,
    const float* __restrict__ bo, float* __restrict__ out)
{
    const int wave = threadIdx.x >> 6, lane = threadIdx.x & 63;
    const int g = lane >> 4, l15 = lane & 15;
    const int ntile = blockIdx.x * 4 + wave;
    const int n = ntile * 16 + l15;
    const int b = n >> 12, nn = n & 4095;

    bf16x8 bfr[4];
#pragma unroll
    for (int h = 0; h < 4; ++h) {
        const char* arow = (const char*)A + (((size_t)(b * 4 + h)) * 4096 + nn) * 64;
        short4v a0 = *(const short4v*)(arow + g * 8);
        short4v a1 = *(const short4v*)(arow + 32 + g * 8);
        bfr[h] = __builtin_shufflevector(a0, a1, 0, 1, 2, 3, 4, 5, 6, 7);
    }
#pragma unroll 1
    for (int ct = 0; ct < 8; ++ct) {
        const int c0 = ct * 16;
        const char* wrow = (const char*)WoT + (size_t)(c0 + l15) * 256;
        f32x4 acc = {0.f, 0.f, 0.f, 0.f};
#pragma unroll
        for (int h = 0; h < 4; ++h) {
            short4v a0 = *(const short4v*)(wrow + h * 64 + g * 8);
            short4v a1 = *(const short4v*)(wrow + h * 64 + 32 + g * 8);
            bf16x8 af = __builtin_shufflevector(a0, a1, 0, 1, 2, 3, 4, 5, 6, 7);
            acc = __builtin_amdgcn_mfma_f32_16x16x32_bf16(af, bfr[h], acc, 0, 0, 0);
        }
        f32x4 bias = *(const f32x4*)(bo + c0 + g * 4);
#pragma unroll
        for (int r = 0; r < 4; ++r) acc[r] += bias[r];
        *(f32x4*)(out + (size_t)n * 128 + c0 + g * 4) = acc;
    }
}

// ---------------------------------------------------------------------------
extern "C" void kernel_launch(void* const* d_in, const int* in_sizes, int n_in,
                              void* d_out, int out_size, void* d_ws, size_t ws_size,
                              hipStream_t stream)
{
    const float* x   = (const float*)d_in[0];
    const int*   adj = (const int*)d_in[1];
    const float* Wq  = (const float*)d_in[2];
    const float* Wk  = (const float*)d_in[3];
    const float* Wv  = (const float*)d_in[4];
    const float* Wo  = (const float*)d_in[5];
    const float* bo  = (const float*)d_in[6];
    float* out = (float*)d_out;

    char* ws = (char*)d_ws;
    uint16_t* Q    = (uint16_t*)(ws);                       // 4 MB
    uint16_t* Kf   = (uint16_t*)(ws + ((size_t)4 << 20));   // 4 MB (fragment order)
    uint16_t* Vf   = (uint16_t*)(ws + ((size_t)8 << 20));   // 4 MB (fragment order)
    uint16_t* AO   = (uint16_t*)(ws + ((size_t)12 << 20));  // 4 MB
    uint32_t* bits = (uint32_t*)(ws + ((size_t)16 << 20));  // 2 MB
    uint16_t* WT   = (uint16_t*)(ws + ((size_t)18 << 20));  // 96 KB
    uint16_t* WoT  = (uint16_t*)(ws + ((size_t)18 << 20) + 98304); // 32 KB

    hipLaunchKernelGGL(pack_kernel, dim3(2048), dim3(256), 0, stream,
                       adj, (uint64_t*)bits, Wq, Wk, Wv, Wo, WT, WoT);
    hipLaunchKernelGGL(qkv_kernel, dim3(256), dim3(256), 0, stream,
                       x, WT, Q, Kf, Vf);
    hipLaunchKernelGGL(attn_kernel, dim3(1024), dim3(512), 0, stream,
                       Q, Kf, Vf, bits, AO);
    hipLaunchKernelGGL(proj_kernel, dim3(256), dim3(256), 0, stream,
                       AO, WoT, bo, out);
}

// Round 6
// 130.132 us; speedup vs baseline: 1.8307x; 1.0234x over previous
//
#include <hip/hip_runtime.h>
#include <stdint.h>

typedef __attribute__((ext_vector_type(4))) short short4v;
typedef __attribute__((ext_vector_type(8))) short bf16x8;
typedef __attribute__((ext_vector_type(4))) float f32x4;
typedef __attribute__((ext_vector_type(2))) uint32_t uint2v;
typedef __attribute__((ext_vector_type(4))) uint32_t uint4v;
typedef __attribute__((ext_vector_type(4))) uint16_t ushort4v;

#define NN 4096

__device__ __forceinline__ uint16_t f2bf(float f) {
    union { float f; uint32_t u; } c; c.f = f;
    uint32_t r = c.u + 0x7FFF + ((c.u >> 16) & 1);   // RNE
    return (uint16_t)(r >> 16);
}

// ---------------------------------------------------------------------------
// Kernel 1: weight transpose -> bf16 (tiny, runs first).
// Wq gets 1/sqrt(32)*log2(e) folded in. grid 256 x 256, 1 elem/thread.
// ---------------------------------------------------------------------------
__global__ __launch_bounds__(256) void wpack_kernel(
    const float* __restrict__ Wq, const float* __restrict__ Wk,
    const float* __restrict__ Wv, const float* __restrict__ Wo,
    uint16_t* __restrict__ WT, uint16_t* __restrict__ WoT)
{
    const int t = blockIdx.x * 256 + threadIdx.x;   // 0..65535
    if (t < 3 * 128 * 128) {
        int j = t >> 7, k = t & 127;
        int m = j >> 7, jj = j & 127;
        const float* W = (m == 0) ? Wq : ((m == 1) ? Wk : Wv);
        float v = W[k * 128 + jj];
        if (m == 0) v *= (0.17677669529663687f * 1.4426950408889634f);
        WT[t] = f2bf(v);
    } else {
        int t2 = t - 3 * 128 * 128;
        int j = t2 >> 7, k = t2 & 127;
        WoT[t2] = f2bf(Wo[k * 128 + j]);
    }
}

// ---------------------------------------------------------------------------
// Kernel 2: FUSED adjacency-pack + QKV projection (independent block ranges
// run concurrently: adjacency is a pure HBM stream, qkv is MFMA compute).
// blocks [0,768):   qkv, split 3 ways (m=0 Q, m=1 K, m=2 V; 8 jt each)
// blocks [768,2816): adjacency -> bitmask
// ---------------------------------------------------------------------------
__global__ __launch_bounds__(256) void adjqkv_kernel(
    const int* __restrict__ adj, uint64_t* __restrict__ bits,
    const float* __restrict__ x, const uint16_t* __restrict__ WT,
    uint16_t* __restrict__ Q, uint16_t* __restrict__ Kf, uint16_t* __restrict__ Vf)
{
    const int blk = blockIdx.x;
    const int tid = threadIdx.x;
    const int wave = tid >> 6, lane = tid & 63;

    if (blk >= 768) {
        // ---- adjacency pack ----
        const int ablk = blk - 768;                    // 0..2047
        const int wid = (ablk * 256 + tid) >> 6;       // 0..8191
        const int TOT = (NN * NN) / 64;                // 262144
        for (int i = wid; i < TOT; i += 8192) {
            int v = adj[(size_t)i * 64 + lane];
            uint64_t m = __ballot(v != 0);
            if (lane == 0) bits[i] = m;
        }
        return;
    }

    // ---- qkv ----
    const int g = lane >> 4, l15 = lane & 15;
    const int m = blk >> 8;                            // 0=Q 1=K 2=V
    const int ntile = (blk & 255) * 4 + wave;          // 0..1023
    const int n = ntile * 16 + l15;
    const int b = n >> 12, nn = n & 4095;

    const char* xrow = (const char*)x + (size_t)n * 512;
    bf16x8 xb[4];
#pragma unroll
    for (int ks = 0; ks < 4; ++ks) {
        f32x4 a = *(const f32x4*)(xrow + ks * 128 + g * 16);
        f32x4 c = *(const f32x4*)(xrow + ks * 128 + 64 + g * 16);
        bf16x8 f;
#pragma unroll
        for (int i = 0; i < 4; ++i) { f[i] = (short)f2bf(a[i]); f[4 + i] = (short)f2bf(c[i]); }
        xb[ks] = f;
    }

#pragma unroll 1
    for (int jt = m * 8; jt < m * 8 + 8; ++jt) {
        const int j0 = jt * 16;
        const bool isV = (m == 2);
        const char* wrow = (const char*)WT + (size_t)(j0 + l15) * 256;
        f32x4 acc = {0.f, 0.f, 0.f, 0.f};
#pragma unroll
        for (int ks = 0; ks < 4; ++ks) {
            short4v a0 = *(const short4v*)(wrow + ks * 64 + g * 8);
            short4v a1 = *(const short4v*)(wrow + ks * 64 + 32 + g * 8);
            bf16x8 af = __builtin_shufflevector(a0, a1, 0, 1, 2, 3, 4, 5, 6, 7);
            acc = isV ? __builtin_amdgcn_mfma_f32_16x16x32_bf16(xb[ks], af, acc, 0, 0, 0)
                      : __builtin_amdgcn_mfma_f32_16x16x32_bf16(af, xb[ks], acc, 0, 0, 0);
        }
        const int bh = b * 4 + ((j0 & 127) >> 5);
        const int half = (j0 >> 4) & 1;
        ushort4v st;
#pragma unroll
        for (int r = 0; r < 4; ++r) st[r] = f2bf(acc[r]);
        if (m == 0) {
            const int d0 = (j0 & 31) + g * 4;
            *(ushort4v*)(Q + ((size_t)bh * 4096 + nn) * 32 + d0) = st;
        } else if (m == 1) {
            *(ushort4v*)(Kf + ((size_t)bh << 17) + (ntile & 255) * 512 + lane * 8 + half * 4) = st;
        } else {
            *(ushort4v*)(Vf + ((size_t)bh << 17) + ((ntile & 255) >> 1) * 1024
                         + half * 512 + lane * 8 + ((ntile & 1) << 2)) = st;
        }
    }
}

// ---------------------------------------------------------------------------
// Kernel 3: flash attention. 256-thr blocks, 32 q-rows (qg=2), key-split 4
// (1024 keys/wave, 16 iters of 64 keys). Low persistent reg state (acc 24 +
// qf 8) targets 5 waves/SIMD. Keys processed in 32-wide halves to halve live
// s/p registers. LDS-free main loop; one combine at end.
// ---------------------------------------------------------------------------
__global__ __launch_bounds__(256) void attn_kernel(
    const uint16_t* __restrict__ Q, const uint16_t* __restrict__ Kf,
    const uint16_t* __restrict__ Vf, const uint32_t* __restrict__ bits,
    uint16_t* __restrict__ O)
{
    __shared__ f32x4 cmb[4][2][2][64];   // [wave][qg][h][lane]
    __shared__ float csum[4][2][64];
    const int tid = threadIdx.x;
    const int wave = tid >> 6, lane = tid & 63;
    const int g = lane >> 4, l15 = lane & 15, gsh = g * 4;
    const int blk = blockIdx.x;
    const int bh = ((blk & 7) << 1) | ((blk >> 3) & 1);   // XCD-cluster bh
    const int qb = blk >> 4;                               // 0..127
    const int q0 = qb * 32;

    const char* Kp = (const char*)Kf + ((size_t)bh << 18) + wave * 65536 + lane * 16;
    const char* Vp = (const char*)Vf + ((size_t)bh << 18) + wave * 65536 + lane * 16;
    const uint32_t* ap0 = bits + (size_t)(q0 + l15) * 128 + wave * 32;
    const uint32_t* ap1 = bits + (size_t)(q0 + 16 + l15) * 128 + wave * 32;

    bf16x8 qf[2];
#pragma unroll
    for (int qg = 0; qg < 2; ++qg) {
        const char* qrow = (const char*)Q + ((size_t)bh * 4096 + q0 + qg * 16 + l15) * 64;
        short4v a0 = *(const short4v*)(qrow + g * 8);
        short4v a1 = *(const short4v*)(qrow + 32 + g * 8);
        qf[qg] = __builtin_shufflevector(a0, a1, 0, 1, 2, 3, 4, 5, 6, 7);
    }

    bf16x8 ones;
#pragma unroll
    for (int i = 0; i < 8; ++i) ones[i] = (short)0x3F80;   // bf16 1.0

    const f32x4 z = {0.f, 0.f, 0.f, 0.f};
    f32x4 o[2][2], sacc[2];
#pragma unroll
    for (int qg = 0; qg < 2; ++qg) { o[qg][0] = z; o[qg][1] = z; sacc[qg] = z; }

#pragma unroll 1
    for (int t = 0; t < 16; ++t) {
        bf16x8 kc[4], vc[4];
#pragma unroll
        for (int j = 0; j < 4; ++j) kc[j] = *(const bf16x8*)(Kp + j * 1024);
#pragma unroll
        for (int i = 0; i < 4; ++i) vc[i] = *(const bf16x8*)(Vp + i * 1024);
        Kp += 4096; Vp += 4096;
        uint2v wc0 = *(const uint2v*)ap0;  ap0 += 2;
        uint2v wc1 = *(const uint2v*)ap1;  ap1 += 2;

#pragma unroll
        for (int qg = 0; qg < 2; ++qg) {
            const uint2v wc = qg ? wc1 : wc0;
#pragma unroll
            for (int half32 = 0; half32 < 2; ++half32) {
                // 32 keys: 2 QK MFMAs
                f32x4 s0 = __builtin_amdgcn_mfma_f32_16x16x32_bf16(kc[half32 * 2], qf[qg], z, 0, 0, 0);
                f32x4 s1 = __builtin_amdgcn_mfma_f32_16x16x32_bf16(kc[half32 * 2 + 1], qf[qg], z, 0, 0, 0);
                uint32_t wlo = (wc[half32]) >> gsh;
                uint32_t whi = (wc[half32]) >> (16 + gsh);
                float p[8];
#pragma unroll
                for (int r = 0; r < 4; ++r) {
                    float pv0 = __builtin_amdgcn_exp2f(s0[r]);
                    int m0 = ((int)(wlo << (31 - r))) >> 31;
                    p[r] = __uint_as_float(__float_as_uint(pv0) & (uint32_t)m0);
                    float pv1 = __builtin_amdgcn_exp2f(s1[r]);
                    int m1 = ((int)(whi << (31 - r))) >> 31;
                    p[4 + r] = __uint_as_float(__float_as_uint(pv1) & (uint32_t)m1);
                }
                uint32_t pk[4];
#pragma unroll
                for (int i = 0; i < 4; ++i) {
                    uint32_t r_;
                    asm("v_cvt_pk_bf16_f32 %0, %1, %2" : "=v"(r_) : "v"(p[2 * i]), "v"(p[2 * i + 1]));
                    pk[i] = r_;
                }
                uint4v u = {pk[0], pk[1], pk[2], pk[3]};
                bf16x8 pf = __builtin_bit_cast(bf16x8, u);
                o[qg][0] = __builtin_amdgcn_mfma_f32_16x16x32_bf16(vc[half32 * 2], pf, o[qg][0], 0, 0, 0);
                o[qg][1] = __builtin_amdgcn_mfma_f32_16x16x32_bf16(vc[half32 * 2 + 1], pf, o[qg][1], 0, 0, 0);
                sacc[qg] = __builtin_amdgcn_mfma_f32_16x16x32_bf16(ones, pf, sacc[qg], 0, 0, 0);
            }
        }
    }

    // combine across the 4 key-split waves
#pragma unroll
    for (int qg = 0; qg < 2; ++qg) {
        cmb[wave][qg][0][lane] = o[qg][0];
        cmb[wave][qg][1][lane] = o[qg][1];
        csum[wave][qg][lane] = sacc[qg][0];
    }
    __syncthreads();
    {
        const int qg = wave >> 1, h = wave & 1;   // each wave finalizes one (qg,h)
        f32x4 a = cmb[0][qg][h][lane] + cmb[1][qg][h][lane]
                + cmb[2][qg][h][lane] + cmb[3][qg][h][lane];
        float sd = csum[0][qg][lane] + csum[1][qg][lane]
                 + csum[2][qg][lane] + csum[3][qg][lane];
        const float inv = 1.0f / sd;
        const int q = q0 + qg * 16 + l15;
        uint16_t* orow = O + ((size_t)bh * 4096 + q) * 32;
        ushort4v st;
#pragma unroll
        for (int r = 0; r < 4; ++r) st[r] = f2bf(a[r] * inv);
        *(ushort4v*)(orow + h * 16 + gsh) = st;
    }
}

// ---------------------------------------------------------------------------
// Kernel 4: output projection, split 2 ways over output columns (grid 512).
// ---------------------------------------------------------------------------
__global__ __launch_bounds__(256) void proj_kernel(
    const uint16_t* __restrict__ A, const uint16_t* __restrict__ WoT,
    const float* __restrict__ bo, float* __restrict__ out)
{
    const int wave = threadIdx.x >> 6, lane = threadIdx.x & 63;
    const int g = lane >> 4, l15 = lane & 15;
    const int blk = blockIdx.x;
    const int ctbase = (blk >> 8) * 4;                 // 0 or 4
    const int ntile = (blk & 255) * 4 + wave;
    const int n = ntile * 16 + l15;
    const int b = n >> 12, nn = n & 4095;

    bf16x8 bfr[4];
#pragma unroll
    for (int h = 0; h < 4; ++h) {
        const char* arow = (const char*)A + (((size_t)(b * 4 + h)) * 4096 + nn) * 64;
        short4v a0 = *(const short4v*)(arow + g * 8);
        short4v a1 = *(const short4v*)(arow + 32 + g * 8);
        bfr[h] = __builtin_shufflevector(a0, a1, 0, 1, 2, 3, 4, 5, 6, 7);
    }
#pragma unroll 1
    for (int ct = ctbase; ct < ctbase + 4; ++ct) {
        const int c0 = ct * 16;
        const char* wrow = (const char*)WoT + (size_t)(c0 + l15) * 256;
        f32x4 acc = {0.f, 0.f, 0.f, 0.f};
#pragma unroll
        for (int h = 0; h < 4; ++h) {
            short4v a0 = *(const short4v*)(wrow + h * 64 + g * 8);
            short4v a1 = *(const short4v*)(wrow + h * 64 + 32 + g * 8);
            bf16x8 af = __builtin_shufflevector(a0, a1, 0, 1, 2, 3, 4, 5, 6, 7);
            acc = __builtin_amdgcn_mfma_f32_16x16x32_bf16(af, bfr[h], acc, 0, 0, 0);
        }
        f32x4 bias = *(const f32x4*)(bo + c0 + g * 4);
#pragma unroll
        for (int r = 0; r < 4; ++r) acc[r] += bias[r];
        *(f32x4*)(out + (size_t)n * 128 + c0 + g * 4) = acc;
    }
}

// ---------------------------------------------------------------------------
extern "C" void kernel_launch(void* const* d_in, const int* in_sizes, int n_in,
                              void* d_out, int out_size, void* d_ws, size_t ws_size,
                              hipStream_t stream)
{
    const float* x   = (const float*)d_in[0];
    const int*   adj = (const int*)d_in[1];
    const float* Wq  = (const float*)d_in[2];
    const float* Wk  = (const float*)d_in[3];
    const float* Wv  = (const float*)d_in[4];
    const float* Wo  = (const float*)d_in[5];
    const float* bo  = (const float*)d_in[6];
    float* out = (float*)d_out;

    char* ws = (char*)d_ws;
    uint16_t* Q    = (uint16_t*)(ws);                       // 4 MB
    uint16_t* Kf   = (uint16_t*)(ws + ((size_t)4 << 20));   // 4 MB (fragment order)
    uint16_t* Vf   = (uint16_t*)(ws + ((size_t)8 << 20));   // 4 MB (fragment order)
    uint16_t* AO   = (uint16_t*)(ws + ((size_t)12 << 20));  // 4 MB
    uint32_t* bits = (uint32_t*)(ws + ((size_t)16 << 20));  // 2 MB
    uint16_t* WT   = (uint16_t*)(ws + ((size_t)18 << 20));  // 96 KB
    uint16_t* WoT  = (uint16_t*)(ws + ((size_t)18 << 20) + 98304); // 32 KB

    hipLaunchKernelGGL(wpack_kernel, dim3(256), dim3(256), 0, stream,
                       Wq, Wk, Wv, Wo, WT, WoT);
    hipLaunchKernelGGL(adjqkv_kernel, dim3(2816), dim3(256), 0, stream,
                       adj, (uint64_t*)bits, x, WT, Q, Kf, Vf);
    hipLaunchKernelGGL(attn_kernel, dim3(2048), dim3(256), 0, stream,
                       Q, Kf, Vf, bits, AO);
    hipLaunchKernelGGL(proj_kernel, dim3(512), dim3(256), 0, stream,
                       AO, WoT, bo, out);
}